// Round 2
// baseline (690.601 us; speedup 1.0000x reference)
//
#include <hip/hip_runtime.h>

// Problem constants (fixed by reference)
constexpr int B_ROWS = 65536;
constexpr int IN_F   = 1024;
constexpr int OUT_F  = 1024;

constexpr int BDIM = 256;          // 4 waves
constexpr int BM = 128, BN = 128, BK = 32;

typedef __bf16 bf16x8 __attribute__((ext_vector_type(8)));
typedef float  f32x4  __attribute__((ext_vector_type(4)));

__device__ __forceinline__ bf16x8 cvt8(f32x4 u0, f32x4 u1) {
    bf16x8 v;
    v[0] = (__bf16)u0[0]; v[1] = (__bf16)u0[1]; v[2] = (__bf16)u0[2]; v[3] = (__bf16)u0[3];
    v[4] = (__bf16)u1[0]; v[5] = (__bf16)u1[1]; v[6] = (__bf16)u1[2]; v[7] = (__bf16)u1[3];
    return v;
}

// async global->LDS, 16B per lane (wave stages 1KB contiguous at uniform lds base)
__device__ __forceinline__ void glds16(const __bf16* g, unsigned char* l) {
    __builtin_amdgcn_global_load_lds(
        (const __attribute__((address_space(1))) unsigned int*)(const void*)g,
        (__attribute__((address_space(3))) unsigned int*)(void*)l,
        16, 0, 0);
}

// Counted barrier: retires the 4 DMAs of the tile about to be computed, leaves
// the next tile's 4 DMAs in flight (vmcnt never drains to 0 in the main loop).
#define BARC() asm volatile("s_waitcnt vmcnt(4) lgkmcnt(0)\n\ts_barrier" ::: "memory")
#define BAR0() asm volatile("s_waitcnt vmcnt(0) lgkmcnt(0)\n\ts_barrier" ::: "memory")

// ---------------- f32 -> bf16 streaming convert (16 elems/thread) --------------------
__global__ __launch_bounds__(256)
void cvt_bf16(const float* __restrict__ in, __bf16* __restrict__ out) {
    const size_t i = ((size_t)blockIdx.x * 256 + threadIdx.x) * 16;
    f32x4 a0 = *(const f32x4*)(in + i);
    f32x4 a1 = *(const f32x4*)(in + i + 4);
    f32x4 a2 = *(const f32x4*)(in + i + 8);
    f32x4 a3 = *(const f32x4*)(in + i + 12);
    *(bf16x8*)(out + i)     = cvt8(a0, a1);
    *(bf16x8*)(out + i + 8) = cvt8(a2, a3);
}

// ---------------- main: pure-DMA staged GEMM + bias + cyclic activation --------------
// LDS: 3 buffers x (A 8KB | B 8KB), MFMA-order layout:
// 16B unit(row,kq) = (row>>4)*64 + kq*16 + (row&15). Every wave-level
// global_load_lds / ds_read_b128 is a contiguous 1KB block -> conflict-free.
__global__ __launch_bounds__(BDIM, 3)
void fused_linear_act(const __bf16* __restrict__ Xb,  // [B_ROWS][IN_F] bf16
                      const __bf16* __restrict__ Wb,  // [OUT_F][IN_F] bf16
                      const float* __restrict__ bias, // [OUT_F]
                      float* __restrict__ O)          // [B_ROWS][OUT_F]
{
    __shared__ __attribute__((aligned(16))) unsigned char lds[3 * 16384];

    const int bx  = blockIdx.x;
    // XCD-aware: 8 consecutive blocks per XCD share one A panel (L2 reuse).
    const int xcd = bx & 7;
    const int idx = bx >> 3;
    const int nt  = idx & 7;
    const int mt  = xcd + 8 * (idx >> 3);
    const int m0 = mt * BM;
    const int n0 = nt * BN;

    const int tid  = threadIdx.x;
    const int lane = tid & 63;
    const int wave = tid >> 6;
    const int wm = (wave >> 1) * 64;
    const int wn = (wave & 1) * 64;
    const int lrow = lane & 15;
    const int quad = lane >> 4;

    f32x4 acc[4][4];
    #pragma unroll
    for (int i = 0; i < 4; ++i)
        #pragma unroll
        for (int j = 0; j < 4; ++j)
            acc[i][j] = (f32x4){0.f, 0.f, 0.f, 0.f};

    // Per-lane pre-swizzled global sources (MFMA-order): wave w stages LDS 1KB
    // blocks {w, w+4} of each operand; within a block lane l holds
    // row = 16*blk + (l&15), k-seg = (l>>4)*8.
    const __bf16* asrc0 = Xb + (size_t)(m0 + 16 * wave + lrow) * IN_F + quad * 8;
    const __bf16* asrc1 = asrc0 + (size_t)64 * IN_F;
    const __bf16* bsrc0 = Wb + (size_t)(n0 + 16 * wave + lrow) * IN_F + quad * 8;
    const __bf16* bsrc1 = bsrc0 + (size_t)64 * IN_F;
    const int wlds = wave * 1024;   // wave-uniform LDS sub-base

    unsigned char* const buf0 = lds;
    unsigned char* const buf1 = lds + 16384;
    unsigned char* const buf2 = lds + 32768;

    const int rdAoff = (wm >> 4) * 1024 + lane * 16;
    const int rdBoff = 8192 + (wn >> 4) * 1024 + lane * 16;

    auto stage = [&](int koff, unsigned char* base) {
        glds16(asrc0 + koff, base + wlds);
        glds16(asrc1 + koff, base + wlds + 4096);
        glds16(bsrc0 + koff, base + 8192 + wlds);
        glds16(bsrc1 + koff, base + 8192 + wlds + 4096);
    };
    auto compute = [&](const unsigned char* base) {
        const unsigned char* ra = base + rdAoff;
        const unsigned char* rb = base + rdBoff;
        bf16x8 af[4], bfr[4];
        #pragma unroll
        for (int t = 0; t < 4; ++t) af[t]  = *(const bf16x8*)(ra + t * 1024);
        #pragma unroll
        for (int t = 0; t < 4; ++t) bfr[t] = *(const bf16x8*)(rb + t * 1024);
        #pragma unroll
        for (int i = 0; i < 4; ++i)
            #pragma unroll
            for (int j = 0; j < 4; ++j)
                acc[i][j] = __builtin_amdgcn_mfma_f32_16x16x32_bf16(af[i], bfr[j], acc[i][j], 0, 0, 0);
    };

    // Prologue: tiles 0,1 in flight. Steady state: at each BARC the oldest 4
    // DMAs (tile k) retire while tile k+1's 4 stay in flight; tile k+2 is then
    // issued -> every tile has ~2 phases of latency cover.
    stage(0,  buf0);
    stage(32, buf1);

    int koff = 64;  // tile 2
    #pragma unroll 1
    for (int it = 0; it < 10; ++it) {
        BARC(); stage(koff, buf2); compute(buf0); koff += 32;
        BARC(); stage(koff, buf0); compute(buf1); koff += 32;
        BARC(); stage(koff, buf1); compute(buf2); koff += 32;
    }
    // k=30,31: no more staging; drain fully before epilogue (no DMA may outlive
    // the block -- LDS gets reallocated).
    BARC(); compute(buf0);
    BAR0(); compute(buf1);

    // Epilogue: bias + cyclic activation; selector = col%4 = lane&3 (branchless).
    // j innermost so consecutive stores cover adjacent 64B segments of the same
    // 4 rows (better L2 write merging).
    const int s = lane & 3;
    const float kmul = (s == 0) ? -2.f : -1.f;
    const float aa   = (s == 0) ?  2.f :  1.f;
    const float cc   = (s == 0) ? -1.f :  0.f;
    const bool  is_sin  = (s == 1);
    const bool  is_relu = (s == 2);

    float bv[4];
    #pragma unroll
    for (int j = 0; j < 4; ++j) bv[j] = bias[n0 + wn + j * 16 + lrow];

    #pragma unroll
    for (int i = 0; i < 4; ++i) {
        #pragma unroll
        for (int r = 0; r < 4; ++r) {
            const int gr = m0 + wm + i * 16 + quad * 4 + r;
            float* op = O + (size_t)gr * OUT_F + n0 + wn + lrow;
            #pragma unroll
            for (int j = 0; j < 4; ++j) {
                const float y = acc[i][j][r] + bv[j];
                const float e = __expf(kmul * y);
                const float g = fmaf(aa, __builtin_amdgcn_rcpf(1.f + e), cc);
                const float sv = __sinf(y);
                const float rv = fmaxf(y, 0.f);
                const float res = is_sin ? sv : (is_relu ? rv : g);
                op[j * 16] = res;
            }
        }
    }
}

// ================= fallback path (ws too small for X): round-1 kernel ================
#define LDS_SYNC() asm volatile("s_waitcnt lgkmcnt(0)\n\ts_barrier" ::: "memory")
#define BAR_CNT() asm volatile("s_waitcnt vmcnt(4) lgkmcnt(0)\n\ts_barrier" ::: "memory")
#define BAR_ALL() asm volatile("s_waitcnt vmcnt(0) lgkmcnt(0)\n\ts_barrier" ::: "memory")

__global__ __launch_bounds__(BDIM, 4)
void fused_linear_act_f32a(const float* __restrict__ X,
                           const __bf16* __restrict__ Wb,
                           const float* __restrict__ bias,
                           float* __restrict__ O)
{
    __shared__ __attribute__((aligned(16))) unsigned char lds[2 * 16384];
    const int bx  = blockIdx.x;
    const int xcd = bx & 7;
    const int idx = bx >> 3;
    const int nt  = idx & 7;
    const int mt  = xcd + 8 * (idx >> 3);
    const int m0 = mt * BM;
    const int n0 = nt * BN;
    const int tid  = threadIdx.x;
    const int lane = tid & 63;
    const int wave = tid >> 6;
    const int wm = (wave >> 1) * 64;
    const int wn = (wave & 1) * 64;
    const int lrow = lane & 15;
    const int quad = lane >> 4;
    const int srow = tid >> 2;
    const int sseg = tid & 3;

    f32x4 acc[4][4];
    #pragma unroll
    for (int i = 0; i < 4; ++i)
        #pragma unroll
        for (int j = 0; j < 4; ++j)
            acc[i][j] = (f32x4){0.f, 0.f, 0.f, 0.f};

    const float* xa = X + (size_t)(m0 + srow) * IN_F + sseg * 8;
    const float* xb = xa + (size_t)64 * IN_F;
    const __bf16* wsrc0 = Wb + (size_t)(n0 + 16 * wave + lrow) * IN_F + quad * 8;
    const __bf16* wsrc1 = wsrc0 + (size_t)64 * IN_F;
    unsigned char* ldsB0 = lds + 8192 + wave * 1024;
    unsigned char* ldsB1 = ldsB0 + 4096;
    unsigned char* wr = &lds[((srow >> 4) * 64 + sseg * 16 + (srow & 15)) * 16];
    const unsigned char* rdA = &lds[(wm >> 4) * 1024 + lane * 16];
    const unsigned char* rdB = &lds[8192 + (wn >> 4) * 1024 + lane * 16];

    f32x4 A00 = *(const f32x4*)(xa);
    f32x4 A01 = *(const f32x4*)(xa + 4);
    f32x4 A10 = *(const f32x4*)(xb);
    f32x4 A11 = *(const f32x4*)(xb + 4);
    glds16(wsrc0, ldsB0);
    glds16(wsrc1, ldsB1);
    __builtin_amdgcn_sched_barrier(0);

    int koffA = 0, koffB = 0;
    auto stageA = [&](int buf) {
        unsigned char* w = wr + buf * 16384;
        *(bf16x8*)(w +    0) = cvt8(A00, A01);
        *(bf16x8*)(w + 4096) = cvt8(A10, A11);
        koffA = (koffA + BK) & (IN_F - 1);
        A00 = *(const f32x4*)(xa + koffA); A01 = *(const f32x4*)(xa + koffA + 4);
        A10 = *(const f32x4*)(xb + koffA); A11 = *(const f32x4*)(xb + koffA + 4);
    };
    auto stageB = [&](int buf) {
        koffB += BK;
        glds16(wsrc0 + koffB, ldsB0 + buf * 16384);
        glds16(wsrc1 + koffB, ldsB1 + buf * 16384);
        __builtin_amdgcn_sched_barrier(0);
    };
    auto compute = [&](int buf) {
        const unsigned char* ra = rdA + buf * 16384;
        const unsigned char* rb = rdB + buf * 16384;
        bf16x8 af[4], bfr[4];
        #pragma unroll
        for (int t = 0; t < 4; ++t) af[t]  = *(const bf16x8*)(ra + t * 1024);
        #pragma unroll
        for (int t = 0; t < 4; ++t) bfr[t] = *(const bf16x8*)(rb + t * 1024);
        #pragma unroll
        for (int i = 0; i < 4; ++i)
            #pragma unroll
            for (int j = 0; j < 4; ++j)
                acc[i][j] = __builtin_amdgcn_mfma_f32_16x16x32_bf16(af[i], bfr[j], acc[i][j], 0, 0, 0);
    };

    #pragma unroll 1
    for (int it = 0; it < IN_F / BK - 2; it += 2) {
        stageA(0); BAR_CNT(); stageB(1); compute(0);
        stageA(1); BAR_CNT(); stageB(0); compute(1);
    }
    stageA(0); BAR_CNT(); stageB(1); compute(0);
    stageA(1); BAR_ALL(); compute(1);

    const int s = lane & 3;
    const float kmul = (s == 0) ? -2.f : -1.f;
    const float aa   = (s == 0) ?  2.f :  1.f;
    const float cc   = (s == 0) ? -1.f :  0.f;
    const bool  is_sin  = (s == 1);
    const bool  is_relu = (s == 2);
    #pragma unroll
    for (int j = 0; j < 4; ++j) {
        const int gc = n0 + wn + j * 16 + lrow;
        const float bvv = bias[gc];
        #pragma unroll
        for (int i = 0; i < 4; ++i) {
            const int gr0 = m0 + wm + i * 16 + quad * 4;
            float* op = O + (size_t)gr0 * OUT_F + gc;
            #pragma unroll
            for (int r = 0; r < 4; ++r) {
                const float y = acc[i][j][r] + bvv;
                const float e = __expf(kmul * y);
                const float g = fmaf(aa, __builtin_amdgcn_rcpf(1.f + e), cc);
                const float sv = __sinf(y);
                const float rv = fmaxf(y, 0.f);
                const float res = is_sin ? sv : (is_relu ? rv : g);
                op[(size_t)r * OUT_F] = res;
            }
        }
    }
}

extern "C" void kernel_launch(void* const* d_in, const int* in_sizes, int n_in,
                              void* d_out, int out_size, void* d_ws, size_t ws_size,
                              hipStream_t stream) {
    const float* X = (const float*)d_in[0];
    const float* W = (const float*)d_in[1];
    const float* b = (const float*)d_in[2];
    float* O = (float*)d_out;

    const size_t nX = (size_t)B_ROWS * IN_F;
    const size_t nW = (size_t)OUT_F * IN_F;
    const size_t need = (nX + nW) * sizeof(__bf16);
    const int grid = (B_ROWS / BM) * (OUT_F / BN);  // 4096 blocks

    if (ws_size >= need) {
        __bf16* Xb = (__bf16*)d_ws;
        __bf16* Wb = Xb + nX;
        cvt_bf16<<<(int)(nX / (256 * 16)), 256, 0, stream>>>(X, Xb);
        cvt_bf16<<<(int)(nW / (256 * 16)), 256, 0, stream>>>(W, Wb);
        fused_linear_act<<<grid, BDIM, 0, stream>>>(Xb, Wb, b, O);
    } else {
        __bf16* Wb = (__bf16*)d_ws;  // 2 MB
        cvt_bf16<<<(int)(nW / (256 * 16)), 256, 0, stream>>>(W, Wb);
        fused_linear_act_f32a<<<grid, BDIM, 0, stream>>>(X, Wb, b, O);
    }
}

// Round 3
// 597.951 us; speedup vs baseline: 1.1549x; 1.1549x over previous
//
#include <hip/hip_runtime.h>

// Problem constants (fixed by reference)
constexpr int B_ROWS = 65536;
constexpr int IN_F   = 1024;
constexpr int OUT_F  = 1024;

constexpr int BDIM = 512;            // 8 waves
constexpr int BM = 256, BN = 256, BK = 64;

typedef __bf16 bf16x8 __attribute__((ext_vector_type(8)));
typedef float  f32x4  __attribute__((ext_vector_type(4)));

__device__ __forceinline__ bf16x8 cvt8(f32x4 u0, f32x4 u1) {
    bf16x8 v;
    v[0] = (__bf16)u0[0]; v[1] = (__bf16)u0[1]; v[2] = (__bf16)u0[2]; v[3] = (__bf16)u0[3];
    v[4] = (__bf16)u1[0]; v[5] = (__bf16)u1[1]; v[6] = (__bf16)u1[2]; v[7] = (__bf16)u1[3];
    return v;
}

// async global->LDS, 16B per lane (wave stages 1KB contiguous at uniform lds base)
__device__ __forceinline__ void glds16(const __bf16* g, unsigned char* l) {
    __builtin_amdgcn_global_load_lds(
        (const __attribute__((address_space(1))) unsigned int*)(const void*)g,
        (__attribute__((address_space(3))) unsigned int*)(void*)l,
        16, 0, 0);
}

// ---------------- W f32 -> bf16 (2 MB, once per launch; W stays L2-resident) --------
__global__ __launch_bounds__(256)
void w_to_bf16(const float* __restrict__ W, __bf16* __restrict__ Wb) {
    const size_t i = ((size_t)blockIdx.x * 256 + threadIdx.x) * 16;
    f32x4 a0 = *(const f32x4*)(W + i);
    f32x4 a1 = *(const f32x4*)(W + i + 4);
    f32x4 a2 = *(const f32x4*)(W + i + 8);
    f32x4 a3 = *(const f32x4*)(W + i + 12);
    *(bf16x8*)(Wb + i)     = cvt8(a0, a1);
    *(bf16x8*)(Wb + i + 8) = cvt8(a2, a3);
}

// ---------------- 256x256 tile, BK=64, 8-wave, 4-phase/K-tile pipelined GEMM ---------
// LDS per buffer (64KB): A at +0 (2 k-halves x 16KB, MFMA-order), B at +32768 (same).
// MFMA-order 1KB block: lane l's fragment bytes at l*16; staged so lane l holds
// row 16*blk+(l&15), k-elems (l>>4)*8..+8. A is reg-staged (f32->cvt->ds_write),
// B is glds16-DMA'd. Per K-tile t (buf = t&1), 4 phases of 16 MFMA; staging of
// tile t+1 -> buf^1 and A-loads of tile t+2 are interleaved into the phases.
// Tile-boundary wait = vmcnt(8): retires the 4 B-DMAs, keeps 8 A-loads in flight.

__global__ __launch_bounds__(BDIM, 2)
void fused_linear_act(const float* __restrict__ X,    // [B_ROWS][IN_F] f32
                      const __bf16* __restrict__ Wb,  // [OUT_F][IN_F] bf16
                      const float* __restrict__ bias, // [OUT_F]
                      float* __restrict__ O)          // [B_ROWS][OUT_F]
{
    __shared__ __attribute__((aligned(16))) unsigned char lds[2 * 65536];  // 128 KB

    const int bx  = blockIdx.x;                 // 1024 blocks
    // XCD-aware: 4 consecutive blocks per XCD share one A panel (1MB, L2 reuse).
    const int xcd = bx & 7;
    const int idx = bx >> 3;
    const int nt  = idx & 3;
    const int mt  = xcd + 8 * (idx >> 2);
    const int m0 = mt * BM;
    const int n0 = nt * BN;

    const int tid  = threadIdx.x;
    const int lane = tid & 63;
    const int wave = tid >> 6;                  // 0..7, 2M x 4N
    const int wm2  = (wave >> 2) * 128;
    const int wn2  = (wave & 3) * 64;
    const int lrow = lane & 15;
    const int quad = lane >> 4;

    // A staging: thread -> (row arow, k-half ah); 8 f32x4 loads -> 4 ds_write_b128
    const int arow = tid >> 1;                  // 0..255
    const int ah   = tid & 1;
    const float* asrc = X + (size_t)(m0 + arow) * IN_F + ah * 32;
    const int awr = ah * 16384 + (arow >> 4) * 1024 + (arow & 15) * 16;

    // B staging: wave w -> k-half (w>>2), rowgroups (w&3)*4 + 0..3
    const __bf16* bs0 = Wb + (size_t)(n0 + (wave & 3) * 64 + lrow) * IN_F
                           + (wave >> 2) * 32 + quad * 8;
    const __bf16* bs1 = bs0 + (size_t)16 * IN_F;
    const __bf16* bs2 = bs0 + (size_t)32 * IN_F;
    const __bf16* bs3 = bs0 + (size_t)48 * IN_F;
    const int bdst = 32768 + (wave >> 2) * 16384 + (wave & 3) * 4096;

    // fragment read offsets (add KS*16384 [+ MH*4096 for A] + frag*1024)
    const int rdA = (wave >> 2) * 8192 + lane * 16;
    const int rdB = 32768 + (wave & 3) * 4096 + lane * 16;

    unsigned char* const b0 = lds;
    unsigned char* const b1 = lds + 65536;

    f32x4 acc[8][4];
    #pragma unroll
    for (int i = 0; i < 8; ++i)
        #pragma unroll
        for (int j = 0; j < 4; ++j)
            acc[i][j] = (f32x4){0.f, 0.f, 0.f, 0.f};

    f32x4 ar0, ar1, ar2, ar3, ar4, ar5, ar6, ar7;   // A prefetch regs (1 tile)
    bf16x8 aq0, aq1, aq2, aq3, bq0, bq1, bq2, bq3;  // per-phase fragments

#define ALOAD_LO(KA) do { \
    ar0 = *(const f32x4*)(asrc + (KA));      ar1 = *(const f32x4*)(asrc + (KA) + 4);  \
    ar2 = *(const f32x4*)(asrc + (KA) + 8);  ar3 = *(const f32x4*)(asrc + (KA) + 12); } while (0)
#define ALOAD_HI(KA) do { \
    ar4 = *(const f32x4*)(asrc + (KA) + 16); ar5 = *(const f32x4*)(asrc + (KA) + 20); \
    ar6 = *(const f32x4*)(asrc + (KA) + 24); ar7 = *(const f32x4*)(asrc + (KA) + 28); } while (0)
#define DSW(NXTB) do { unsigned char* _w = (NXTB) + awr; \
    *(bf16x8*)(_w)       = cvt8(ar0, ar1); \
    *(bf16x8*)(_w + 256) = cvt8(ar2, ar3); \
    *(bf16x8*)(_w + 512) = cvt8(ar4, ar5); \
    *(bf16x8*)(_w + 768) = cvt8(ar6, ar7); } while (0)
#define GLDSB(NXTB, KB) do { unsigned char* _d = (NXTB) + bdst; \
    glds16(bs0 + (KB), _d);        glds16(bs1 + (KB), _d + 1024); \
    glds16(bs2 + (KB), _d + 2048); glds16(bs3 + (KB), _d + 3072); } while (0)
#define READ_A(CURB, KS, MH) do { \
    const unsigned char* _ra = (CURB) + rdA + (KS) * 16384 + (MH) * 4096; \
    aq0 = *(const bf16x8*)(_ra);        aq1 = *(const bf16x8*)(_ra + 1024); \
    aq2 = *(const bf16x8*)(_ra + 2048); aq3 = *(const bf16x8*)(_ra + 3072); } while (0)
#define READ_B(CURB, KS) do { \
    const unsigned char* _rb = (CURB) + rdB + (KS) * 16384; \
    bq0 = *(const bf16x8*)(_rb);        bq1 = *(const bf16x8*)(_rb + 1024); \
    bq2 = *(const bf16x8*)(_rb + 2048); bq3 = *(const bf16x8*)(_rb + 3072); } while (0)
#define MFMA1(MH, I, J) acc[(MH)*4+(I)][(J)] = \
    __builtin_amdgcn_mfma_f32_16x16x32_bf16(aq##I, bq##J, acc[(MH)*4+(I)][(J)], 0, 0, 0)
#define MFMAQ(MH) do { __builtin_amdgcn_s_setprio(1); \
    MFMA1(MH,0,0); MFMA1(MH,0,1); MFMA1(MH,0,2); MFMA1(MH,0,3); \
    MFMA1(MH,1,0); MFMA1(MH,1,1); MFMA1(MH,1,2); MFMA1(MH,1,3); \
    MFMA1(MH,2,0); MFMA1(MH,2,1); MFMA1(MH,2,2); MFMA1(MH,2,3); \
    MFMA1(MH,3,0); MFMA1(MH,3,1); MFMA1(MH,3,2); MFMA1(MH,3,3); \
    __builtin_amdgcn_s_setprio(0); } while (0)
#define VM8    asm volatile("s_waitcnt vmcnt(8)" ::: "memory")
#define VM0    asm volatile("s_waitcnt vmcnt(0)" ::: "memory")
#define VMNONE ((void)0)

// Round t: compute tile t from CURB; stage tile t+1 -> NXTB (glds B + dsw A from
// regs); issue A-loads for tile t+2. Phase = {issues; ds_reads; barrier; 16 MFMA}.
#define ROUND(CURB, NXTB, DO_GLDS, KB, DO_DSW, DO_ALOAD, KA, VMW) do { \
    /* P0 */ \
    if (DO_GLDS) GLDSB(NXTB, KB); \
    READ_B(CURB, 0); READ_A(CURB, 0, 0); \
    __builtin_amdgcn_s_barrier(); \
    MFMAQ(0); \
    /* P1 */ \
    if (DO_DSW) DSW(NXTB); \
    if (DO_ALOAD) ALOAD_LO(KA); \
    READ_A(CURB, 0, 1); \
    __builtin_amdgcn_s_barrier(); \
    MFMAQ(1); \
    /* P2 */ \
    if (DO_ALOAD) ALOAD_HI(KA); \
    READ_B(CURB, 1); READ_A(CURB, 1, 0); \
    __builtin_amdgcn_s_barrier(); \
    MFMAQ(0); \
    /* P3 */ \
    READ_A(CURB, 1, 1); \
    asm volatile("s_waitcnt lgkmcnt(0)" ::: "memory"); \
    VMW; \
    __builtin_amdgcn_s_barrier(); \
    MFMAQ(1); \
} while (0)

    // Prologue: tile0 fully staged into b0; tile1's A-regs loaded; B(0) retired.
    ALOAD_LO(0); ALOAD_HI(0);
    GLDSB(b0, 0);
    DSW(b0);                       // compiler inserts the vmcnt for ar* here
    ALOAD_LO(64); ALOAD_HI(64);
    asm volatile("s_waitcnt vmcnt(8) lgkmcnt(0)" ::: "memory");  // retire glds(B0)
    __builtin_amdgcn_s_barrier();

    // Steady rounds 0..13 (16 K-tiles total)
    #pragma unroll 1
    for (int t = 0; t < 14; t += 2) {
        const int kb0 = (t + 1) * 64, ka0 = (t + 2) * 64;
        ROUND(b0, b1, true, kb0, true, true, ka0, VM8);
        const int kb1 = (t + 2) * 64, ka1 = (t + 3) * 64;
        ROUND(b1, b0, true, kb1, true, true, ka1, VM8);
    }
    // Round 14: stage tile15 (ar holds it), no further A-loads -> full drain once.
    ROUND(b0, b1, true, 15 * 64, true, false, 0, VM0);
    // Round 15: pure compute.
    ROUND(b1, b0, false, 0, false, false, 0, VMNONE);

    // Epilogue: bias + cyclic activation; selector = col%4 = lane&3 (branchless)
    const int s = lane & 3;
    const float kmul = (s == 0) ? -2.f : -1.f;
    const float aa   = (s == 0) ?  2.f :  1.f;
    const float cc   = (s == 0) ? -1.f :  0.f;
    const bool  is_sin  = (s == 1);
    const bool  is_relu = (s == 2);

    float bv[4];
    #pragma unroll
    for (int fn = 0; fn < 4; ++fn) bv[fn] = bias[n0 + wn2 + fn * 16 + lrow];

    #pragma unroll
    for (int fm = 0; fm < 8; ++fm) {
        #pragma unroll
        for (int r = 0; r < 4; ++r) {
            const int gr = m0 + wm2 + fm * 16 + quad * 4 + r;
            float* op = O + (size_t)gr * OUT_F + n0 + wn2 + lrow;
            #pragma unroll
            for (int fn = 0; fn < 4; ++fn) {
                const float y = acc[fm][fn][r] + bv[fn];
                const float e = __expf(kmul * y);
                const float g = fmaf(aa, __builtin_amdgcn_rcpf(1.f + e), cc);
                const float sv = __sinf(y);
                const float rv = fmaxf(y, 0.f);
                const float res = is_sin ? sv : (is_relu ? rv : g);
                op[fn * 16] = res;
            }
        }
    }
}

extern "C" void kernel_launch(void* const* d_in, const int* in_sizes, int n_in,
                              void* d_out, int out_size, void* d_ws, size_t ws_size,
                              hipStream_t stream) {
    const float* X = (const float*)d_in[0];
    const float* W = (const float*)d_in[1];
    const float* b = (const float*)d_in[2];
    float* O = (float*)d_out;
    __bf16* Wb = (__bf16*)d_ws;   // 2 MB workspace for bf16 W

    const size_t nW = (size_t)OUT_F * IN_F;
    w_to_bf16<<<(int)(nW / (256 * 16)), 256, 0, stream>>>(W, Wb);

    const int grid = (B_ROWS / BM) * (OUT_F / BN);  // 1024 blocks
    fused_linear_act<<<grid, BDIM, 0, stream>>>(X, Wb, b, O);
}